// Round 3
// baseline (820.129 us; speedup 1.0000x reference)
//
#include <hip/hip_runtime.h>

typedef unsigned short ushort_t;
typedef unsigned int uint_t;
typedef __bf16 bf16x8 __attribute__((ext_vector_type(8)));
typedef float f32x4 __attribute__((ext_vector_type(4)));
typedef unsigned int u32x4 __attribute__((ext_vector_type(4)));

#define B_SZ 32
#define N_SZ 512
#define FD_SZ 768
#define HD_SZ 384
#define G_SZ 3
#define M_SZ (B_SZ * N_SZ)   // 16384
#define ALPHA_LR 0.2f
#define NEGV -9.0e15f

__device__ __forceinline__ float bflo(uint_t u) { return __uint_as_float(u << 16); }
__device__ __forceinline__ float bfhi(uint_t u) { return __uint_as_float(u & 0xffff0000u); }
__device__ __forceinline__ float bf2f(ushort_t u) { return __uint_as_float(((uint_t)u) << 16); }
__device__ __forceinline__ ushort_t f2bf(float f) {
  uint_t x = __float_as_uint(f);
  return (ushort_t)((x + 0x7fffu + ((x >> 16) & 1u)) >> 16);
}
__device__ __forceinline__ u32x4 pack8(f32x4 lo, f32x4 hi) {
  union { ushort_t us[8]; u32x4 v; } pk;
  pk.us[0] = f2bf(lo.x); pk.us[1] = f2bf(lo.y); pk.us[2] = f2bf(lo.z); pk.us[3] = f2bf(lo.w);
  pk.us[4] = f2bf(hi.x); pk.us[5] = f2bf(hi.y); pk.us[6] = f2bf(hi.z); pk.us[7] = f2bf(hi.w);
  return pk.v;
}

// ---------------------------------------------------------------------------
// Transpose + downcast: dst[c*R + r] = bf16(src[r*C + c]), batched over z.
// ---------------------------------------------------------------------------
__global__ __launch_bounds__(256) void transpose_f2b(
    const float* __restrict__ src, ushort_t* __restrict__ dst, int R, int C) {
  size_t total = (size_t)R * C;
  size_t base = (size_t)blockIdx.z * total;
  size_t i = (size_t)blockIdx.x * 256 + threadIdx.x;
  if (i < total) {
    int r = (int)(i / C), c = (int)(i % C);
    dst[base + (size_t)c * R + r] = f2bf(src[base + i]);
  }
}

// ---------------------------------------------------------------------------
// Content gates: cg[n][g] = softmax_g( mean_b(x[b,n,:]) @ gate_w + gate_b )
// ---------------------------------------------------------------------------
__global__ __launch_bounds__(256) void gate_kernel(
    const float* __restrict__ x, const float* __restrict__ gate_w,
    const float* __restrict__ gate_b, float* __restrict__ cg) {
  int n = blockIdx.x;
  int tid = threadIdx.x;
  float a0 = 0.f, a1 = 0.f, a2 = 0.f;
  for (int f = tid; f < FD_SZ; f += 256) {
    float s = 0.f;
#pragma unroll
    for (int b = 0; b < B_SZ; b++) s += x[((size_t)b * N_SZ + n) * FD_SZ + f];
    float avg = s * (1.0f / B_SZ);
    a0 += avg * gate_w[f * 3 + 0];
    a1 += avg * gate_w[f * 3 + 1];
    a2 += avg * gate_w[f * 3 + 2];
  }
  for (int m = 1; m < 64; m <<= 1) {
    a0 += __shfl_xor(a0, m, 64);
    a1 += __shfl_xor(a1, m, 64);
    a2 += __shfl_xor(a2, m, 64);
  }
  __shared__ float red[3][4];
  int wave = tid >> 6, lane = tid & 63;
  if (lane == 0) { red[0][wave] = a0; red[1][wave] = a1; red[2][wave] = a2; }
  __syncthreads();
  if (tid == 0) {
    float l0 = red[0][0] + red[0][1] + red[0][2] + red[0][3] + gate_b[0];
    float l1 = red[1][0] + red[1][1] + red[1][2] + red[1][3] + gate_b[1];
    float l2 = red[2][0] + red[2][1] + red[2][2] + red[2][3] + gate_b[2];
    float mx = fmaxf(l0, fmaxf(l1, l2));
    float e0 = __expf(l0 - mx), e1 = __expf(l1 - mx), e2 = __expf(l2 - mx);
    float inv = 1.0f / (e0 + e1 + e2);
    cg[n * 3 + 0] = e0 * inv;
    cg[n * 3 + 1] = e1 * inv;
    cg[n * 3 + 2] = e2 * inv;
  }
}

// ---------------------------------------------------------------------------
// MFMA bf16 GEMM: C[M,Nc] = A[M,K] @ B[K,Nc] (+bias, +relu).
// A row-major [M,K]: f32 (downcast in staging) if AF32, else bf16.
// Bt row-major [Nc,K] bf16. 128x128 tile, BK=32, 4 waves 64x64 each.
// ---------------------------------------------------------------------------
template <bool AF32, bool RELU, bool OUTBF16, bool HASBIAS>
__global__ __launch_bounds__(256) void gemm_kernel(
    const void* __restrict__ Av, size_t strideA,
    const ushort_t* __restrict__ Bt, size_t strideB,
    const float* __restrict__ bias,
    void* __restrict__ Cv, size_t strideC,
    int M, int K, int Nc) {
  __shared__ __attribute__((aligned(16))) ushort_t As[128 * 32];
  __shared__ __attribute__((aligned(16))) ushort_t Bs[128 * 32];
  int tid = threadIdx.x, wave = tid >> 6, lane = tid & 63;
  int m0 = blockIdx.y * 128, n0 = blockIdx.x * 128;
  const float* Abf32 = (const float*)Av + (size_t)blockIdx.z * strideA;
  const ushort_t* Abb16 = (const ushort_t*)Av + (size_t)blockIdx.z * strideA;
  const ushort_t* Bb = Bt + (size_t)blockIdx.z * strideB;

  f32x4 acc[4][4];
  f32x4 z4 = {0.f, 0.f, 0.f, 0.f};
#pragma unroll
  for (int i = 0; i < 4; i++)
#pragma unroll
    for (int j = 0; j < 4; j++) acc[i][j] = z4;

  int wm = (wave & 1) * 64, wn = (wave >> 1) * 64;
  int srow = lane >> 2, schk = (lane & 3) * 8;

  for (int kt = 0; kt < K; kt += 32) {
    u32x4 av[2], bv[2];
#pragma unroll
    for (int i = 0; i < 2; i++) {
      int row = m0 + wave * 32 + i * 16 + srow;
      if (AF32) {
        const float* ap = Abf32 + (size_t)row * K + kt + schk;
        f32x4 lo = *(const f32x4*)ap;
        f32x4 hi = *(const f32x4*)(ap + 4);
        av[i] = pack8(lo, hi);
      } else {
        av[i] = *(const u32x4*)(Abb16 + (size_t)row * K + kt + schk);
      }
      bv[i] = *(const u32x4*)(Bb + (size_t)(n0 + wave * 32 + i * 16 + srow) * K + kt + schk);
    }
    __syncthreads();  // previous tile's frag reads done
#pragma unroll
    for (int i = 0; i < 2; i++) {
      int rowBase = wave * 32 + i * 16;
      *(u32x4*)(As + rowBase * 32 + lane * 8) = av[i];
      *(u32x4*)(Bs + rowBase * 32 + lane * 8) = bv[i];
    }
    __syncthreads();
    bf16x8 af[4], bfr[4];
#pragma unroll
    for (int t = 0; t < 4; t++) {
      af[t] = *(const bf16x8*)(As + (wm + t * 16 + (lane & 15)) * 32 + (lane >> 4) * 8);
      bfr[t] = *(const bf16x8*)(Bs + (wn + t * 16 + (lane & 15)) * 32 + (lane >> 4) * 8);
    }
#pragma unroll
    for (int mt = 0; mt < 4; mt++)
#pragma unroll
      for (int nt = 0; nt < 4; nt++)
        acc[mt][nt] = __builtin_amdgcn_mfma_f32_16x16x32_bf16(af[mt], bfr[nt], acc[mt][nt], 0, 0, 0);
  }

#pragma unroll
  for (int mt = 0; mt < 4; mt++) {
#pragma unroll
    for (int nt = 0; nt < 4; nt++) {
      int gn = n0 + wn + nt * 16 + (lane & 15);
      float bvs = HASBIAS ? bias[gn] : 0.f;
#pragma unroll
      for (int r2 = 0; r2 < 4; r2++) {
        int gm = m0 + wm + mt * 16 + (lane >> 4) * 4 + r2;
        float v = acc[mt][nt][r2] + bvs;
        if (RELU) v = v > 0.f ? v : 0.f;
        size_t off = (size_t)blockIdx.z * strideC + (size_t)gm * Nc + gn;
        if (OUTBF16) ((ushort_t*)Cv)[off] = f2bf(v);
        else ((float*)Cv)[off] = v;
      }
    }
  }
}

// ---------------------------------------------------------------------------
// e1[g,m] = h[g,m,:] . a[g,:HD];  e2[g,m] = h[g,m,:] . a[g,HD:]  (a is f32)
// ---------------------------------------------------------------------------
__global__ __launch_bounds__(256) void e12_kernel(
    const ushort_t* __restrict__ hbf, const float* __restrict__ a,
    float* __restrict__ e1, float* __restrict__ e2) {
  int tid = threadIdx.x, wave = tid >> 6, lane = tid & 63;
  int rowid = blockIdx.x * 4 + wave;  // [0, G*M)
  int g = rowid / M_SZ;
  const ushort_t* h = hbf + (size_t)rowid * HD_SZ;
  const float* a1 = a + g * 2 * HD_SZ;
  const float* a2 = a1 + HD_SZ;
  float s1 = 0.f, s2 = 0.f;
#pragma unroll
  for (int k = 0; k < 3; k++) {
    int idx = k * 128 + lane * 2;
    uint_t u = *(const uint_t*)(h + idx);
    float h0 = bflo(u), h1 = bfhi(u);
    s1 += h0 * a1[idx] + h1 * a1[idx + 1];
    s2 += h0 * a2[idx] + h1 * a2[idx + 1];
  }
  for (int m = 1; m < 64; m <<= 1) {
    s1 += __shfl_xor(s1, m, 64);
    s2 += __shfl_xor(s2, m, 64);
  }
  if (lane == 0) { e1[rowid] = s1; e2[rowid] = s2; }
}

// ---------------------------------------------------------------------------
// Attention + ELU + LN1 + g-weighted fuse. One block = one b, 16 query rows.
// ---------------------------------------------------------------------------
__global__ __launch_bounds__(256) void attn_kernel(
    const int* __restrict__ adj, const ushort_t* __restrict__ hbf,
    const float* __restrict__ e1, const float* __restrict__ e2,
    const float* __restrict__ cg, const float* __restrict__ log_unc,
    const float* __restrict__ ln1g, const float* __restrict__ ln1b,
    ushort_t* __restrict__ fusedbf) {
  __shared__ __attribute__((aligned(16))) float p[16][512];        // 32 KB
  __shared__ __attribute__((aligned(16))) ushort_t hs[32 * HD_SZ]; // 24 KB
  __shared__ float e2s[512];
  __shared__ float e1r[16], lr[16];
  __shared__ float lng[HD_SZ], lnb[HD_SZ];
  __shared__ float cgr[16][3];

  int tid = threadIdx.x, wave = tid >> 6, lane = tid & 63;
  int b = blockIdx.y, i0 = blockIdx.x * 16;
  int r = tid >> 4;                 // query row within tile (16 threads per row)
  int cbase = (tid & 15) * 8;       // column group base

  float iv0 = 1.f / (__expf(log_unc[0]) + 1e-8f);
  float iv1 = 1.f / (__expf(log_unc[1]) + 1e-8f);
  float iv2 = 1.f / (__expf(log_unc[2]) + 1e-8f);
  float mxa = fmaxf(iv0, fmaxf(iv1, iv2));
  float w0 = __expf(iv0 - mxa), w1 = __expf(iv1 - mxa), w2 = __expf(iv2 - mxa);
  float wsum = 1.f / (w0 + w1 + w2);
  float attw[3] = {w0 * wsum, w1 * wsum, w2 * wsum};

  for (int idx = tid; idx < HD_SZ; idx += 256) {
    lng[idx] = ln1g[idx];
    lnb[idx] = ln1b[idx];
  }
  if (tid < 48) cgr[tid / 3][tid % 3] = cg[(i0 + tid / 3) * 3 + tid % 3];

  float facc[24];
#pragma unroll
  for (int t = 0; t < 24; t++) facc[t] = 0.f;

  for (int g = 0; g < G_SZ; g++) {
    __syncthreads();  // protect LDS from previous-iteration readers
    if (tid < 16) e1r[tid] = e1[((size_t)g * B_SZ + b) * N_SZ + i0 + tid];
    for (int idx = tid; idx < N_SZ; idx += 256)
      e2s[idx] = e2[((size_t)g * B_SZ + b) * N_SZ + idx];
    __syncthreads();
    // scores: lrelu(e1_i + e2_j), masked
    for (int idx = tid; idx < 16 * N_SZ; idx += 256) {
      int rr = idx >> 9, j = idx & 511;
      float s = e1r[rr] + e2s[j];
      s = s > 0.f ? s : ALPHA_LR * s;
      int ad = adj[((size_t)g * N_SZ + i0 + rr) * N_SZ + j];
      ((float*)p)[idx] = ad > 0 ? s : NEGV;
    }
    __syncthreads();
    // softmax (unnormalized exp in p, row sums in lr); wave w owns rows 4w..4w+3
    for (int rr = 0; rr < 4; rr++) {
      int rw = wave * 4 + rr;
      float m = -3.0e38f;
      float sv[8];
#pragma unroll
      for (int jj = 0; jj < 8; jj++) {
        sv[jj] = p[rw][lane + jj * 64];
        m = fmaxf(m, sv[jj]);
      }
      for (int msk = 1; msk < 64; msk <<= 1) m = fmaxf(m, __shfl_xor(m, msk, 64));
      float sum = 0.f;
#pragma unroll
      for (int jj = 0; jj < 8; jj++) {
        float e = __expf(sv[jj] - m);
        p[rw][lane + jj * 64] = e;
        sum += e;
      }
      for (int msk = 1; msk < 64; msk <<= 1) sum += __shfl_xor(sum, msk, 64);
      if (lane == 0) lr[rw] = sum;
    }
    // att @ h  (fp32 VALU, V staged as bf16 tiles)
    float acc[24];
#pragma unroll
    for (int t = 0; t < 24; t++) acc[t] = 0.f;
    const ushort_t* hsrc = hbf + ((size_t)g * B_SZ + b) * N_SZ * HD_SZ;
    for (int jt = 0; jt < N_SZ; jt += 32) {
      u32x4 hv[6];
#pragma unroll
      for (int is = 0; is < 6; is++) {
        int off = (wave * 6 + is) * 512 + lane * 8;
        hv[is] = *(const u32x4*)(hsrc + (size_t)jt * HD_SZ + off);
      }
      __syncthreads();  // previous tile consumed
#pragma unroll
      for (int is = 0; is < 6; is++) {
        int off = (wave * 6 + is) * 512 + lane * 8;
        *(u32x4*)(hs + off) = hv[is];
      }
      __syncthreads();
#pragma unroll 4
      for (int j2 = 0; j2 < 32; j2++) {
        float pj = p[r][jt + j2];
        const ushort_t* hp = hs + j2 * HD_SZ + cbase;
#pragma unroll
        for (int k = 0; k < 3; k++) {
          u32x4 uv = *(const u32x4*)(hp + k * 128);
          acc[k * 8 + 0] += pj * bflo(uv.x);
          acc[k * 8 + 1] += pj * bfhi(uv.x);
          acc[k * 8 + 2] += pj * bflo(uv.y);
          acc[k * 8 + 3] += pj * bfhi(uv.y);
          acc[k * 8 + 4] += pj * bflo(uv.z);
          acc[k * 8 + 5] += pj * bfhi(uv.z);
          acc[k * 8 + 6] += pj * bflo(uv.w);
          acc[k * 8 + 7] += pj * bfhi(uv.w);
        }
      }
      __syncthreads();
    }
    // epilogue: normalize, ELU, LN over HD (16-lane groups share a row), weight
    float linv = 1.0f / lr[r];
    float o[24];
    float s1 = 0.f, s2 = 0.f;
#pragma unroll
    for (int t = 0; t < 24; t++) {
      float v = acc[t] * linv;
      v = v > 0.f ? v : __expf(v) - 1.f;
      o[t] = v;
      s1 += v;
      s2 += v * v;
    }
#pragma unroll
    for (int msk = 1; msk < 16; msk <<= 1) {
      s1 += __shfl_xor(s1, msk, 64);
      s2 += __shfl_xor(s2, msk, 64);
    }
    float mean = s1 * (1.f / HD_SZ);
    float var = s2 * (1.f / HD_SZ) - mean * mean;
    float rs = rsqrtf(var + 1e-5f);
    float wgt = 0.7f * attw[g] + 0.3f * cgr[r][g];
#pragma unroll
    for (int k = 0; k < 3; k++)
#pragma unroll
      for (int jj = 0; jj < 8; jj++) {
        int c = cbase + k * 128 + jj;
        facc[k * 8 + jj] += wgt * ((o[k * 8 + jj] - mean) * rs * lng[c] + lnb[c]);
      }
  }
  // write fused (bf16)
  size_t rowo = ((size_t)b * N_SZ + i0 + r) * HD_SZ;
#pragma unroll
  for (int k = 0; k < 3; k++) {
    union { ushort_t us[8]; u32x4 v; } pk;
#pragma unroll
    for (int jj = 0; jj < 8; jj++) pk.us[jj] = f2bf(facc[k * 8 + jj]);
    *(u32x4*)(fusedbf + rowo + cbase + k * 128) = pk.v;
  }
}

// ---------------------------------------------------------------------------
// LN2 + residual sigmoid gate. One block per (b,n) row. proj bf16, x/out f32.
// ---------------------------------------------------------------------------
__global__ __launch_bounds__(256) void final_kernel(
    const ushort_t* __restrict__ projbf, const float* __restrict__ x,
    const float* __restrict__ ln2g, const float* __restrict__ ln2b,
    float* __restrict__ out) {
  int row = blockIdx.x;
  int tid = threadIdx.x, wave = tid >> 6, lane = tid & 63;
  const ushort_t* pr = projbf + (size_t)row * FD_SZ;
  const float* xr = x + (size_t)row * FD_SZ;
  float v[3], xv[3];
  float s1 = 0.f, s2 = 0.f;
#pragma unroll
  for (int k = 0; k < 3; k++) {
    int c = tid + k * 256;
    v[k] = bf2f(pr[c]);
    xv[k] = xr[c];
    s1 += v[k];
    s2 += v[k] * v[k];
  }
  for (int m = 1; m < 64; m <<= 1) {
    s1 += __shfl_xor(s1, m, 64);
    s2 += __shfl_xor(s2, m, 64);
  }
  __shared__ float rs1[4], rs2[4], rdt[4];
  if (lane == 0) { rs1[wave] = s1; rs2[wave] = s2; }
  __syncthreads();
  s1 = rs1[0] + rs1[1] + rs1[2] + rs1[3];
  s2 = rs2[0] + rs2[1] + rs2[2] + rs2[3];
  float mean = s1 * (1.f / FD_SZ);
  float var = s2 * (1.f / FD_SZ) - mean * mean;
  float rstd = rsqrtf(var + 1e-5f);
  float dot = 0.f;
  float pn[3];
#pragma unroll
  for (int k = 0; k < 3; k++) {
    int c = tid + k * 256;
    pn[k] = (v[k] - mean) * rstd * ln2g[c] + ln2b[c];
    dot += pn[k] * xv[k];
  }
  for (int m = 1; m < 64; m <<= 1) dot += __shfl_xor(dot, m, 64);
  if (lane == 0) rdt[wave] = dot;
  __syncthreads();
  dot = rdt[0] + rdt[1] + rdt[2] + rdt[3];
  float gv = 1.f / (1.f + __expf(-dot * (1.0f / 27.712812921102035f)));  // /sqrt(768)
#pragma unroll
  for (int k = 0; k < 3; k++) {
    int c = tid + k * 256;
    out[(size_t)row * FD_SZ + c] = gv * xv[k] + (1.f - gv) * pn[k];
  }
}

// ---------------------------------------------------------------------------
extern "C" void kernel_launch(void* const* d_in, const int* in_sizes, int n_in,
                              void* d_out, int out_size, void* d_ws, size_t ws_size,
                              hipStream_t stream) {
  (void)in_sizes; (void)n_in; (void)out_size; (void)ws_size;
  const float* x = (const float*)d_in[0];
  const int* adj = (const int*)d_in[1];
  const float* W = (const float*)d_in[2];
  const float* a = (const float*)d_in[3];
  const float* log_unc = (const float*)d_in[4];
  const float* gate_w = (const float*)d_in[5];
  const float* gate_b = (const float*)d_in[6];
  const float* ln1g = (const float*)d_in[7];
  const float* ln1b = (const float*)d_in[8];
  const float* w1 = (const float*)d_in[9];
  const float* b1 = (const float*)d_in[10];
  const float* w2 = (const float*)d_in[11];
  const float* b2 = (const float*)d_in[12];
  const float* ln2g = (const float*)d_in[13];
  const float* ln2b = (const float*)d_in[14];

  // Workspace (peak 53,385,216 B ≈ 50.9 MiB, liveness-overlapped):
  //  [0          ) Wt      1,769,472   (bf16 [G][HD][FD])
  //  [1,769,472  ) w1t     294,912
  //  [2,064,384  ) w2t     589,824
  //  [2,654,208  ) cg      6,144
  //  [2,660,352  ) e1      196,608
  //  [2,856,960  ) e2      196,608
  //  [3,053,568  ) fusedbf 12,582,912  (attn -> t1 GEMM)
  //  [15,636,480 ) hbf     37,748,736  (h GEMM -> attn); then reused:
  //  [15,636,480 )   t1bf    12,582,912
  //  [28,219,392 )   projbf  25,165,824
  char* ws = (char*)d_ws;
  ushort_t* Wt      = (ushort_t*)(ws + 0);
  ushort_t* w1t     = (ushort_t*)(ws + 1769472);
  ushort_t* w2t     = (ushort_t*)(ws + 2064384);
  float*    cg      = (float*)(ws + 2654208);
  float*    e1      = (float*)(ws + 2660352);
  float*    e2      = (float*)(ws + 2856960);
  ushort_t* fusedbf = (ushort_t*)(ws + 3053568);
  ushort_t* hbf     = (ushort_t*)(ws + 15636480);
  ushort_t* t1bf    = (ushort_t*)(ws + 15636480);   // over dead hbf
  ushort_t* projbf  = (ushort_t*)(ws + 28219392);   // over dead hbf

  transpose_f2b<<<dim3(1152, 1, 3), 256, 0, stream>>>(W, Wt, FD_SZ, HD_SZ);
  transpose_f2b<<<dim3(576, 1, 1), 256, 0, stream>>>(w1, w1t, HD_SZ, HD_SZ);
  transpose_f2b<<<dim3(1152, 1, 1), 256, 0, stream>>>(w2, w2t, HD_SZ, FD_SZ);

  gate_kernel<<<dim3(N_SZ), 256, 0, stream>>>(x, gate_w, gate_b, cg);

  // h[g] = x @ W[g]   (A = x f32, downcast in staging)
  gemm_kernel<true, false, true, false><<<dim3(3, 128, 3), 256, 0, stream>>>(
      x, 0, Wt, (size_t)HD_SZ * FD_SZ, nullptr, hbf, (size_t)M_SZ * HD_SZ,
      M_SZ, FD_SZ, HD_SZ);

  e12_kernel<<<dim3(G_SZ * M_SZ / 4), 256, 0, stream>>>(hbf, a, e1, e2);

  attn_kernel<<<dim3(N_SZ / 16, B_SZ), 256, 0, stream>>>(
      adj, hbf, e1, e2, cg, log_unc, ln1g, ln1b, fusedbf);

  // t1 = relu(fused @ w1 + b1)
  gemm_kernel<false, true, true, true><<<dim3(3, 128, 1), 256, 0, stream>>>(
      fusedbf, 0, w1t, 0, b1, t1bf, 0, M_SZ, HD_SZ, HD_SZ);
  // proj = t1 @ w2 + b2 (bf16 out)
  gemm_kernel<false, false, true, true><<<dim3(6, 128, 1), 256, 0, stream>>>(
      t1bf, 0, w2t, 0, b2, projbf, 0, M_SZ, HD_SZ, FD_SZ);

  final_kernel<<<dim3(M_SZ), 256, 0, stream>>>(projbf, x, ln2g, ln2b, (float*)d_out);
}

// Round 5
// 430.099 us; speedup vs baseline: 1.9068x; 1.9068x over previous
//
#include <hip/hip_runtime.h>

typedef unsigned short ushort_t;
typedef unsigned int uint_t;
typedef __bf16 bf16x8 __attribute__((ext_vector_type(8)));
typedef float f32x4 __attribute__((ext_vector_type(4)));
typedef unsigned int u32x4 __attribute__((ext_vector_type(4)));
typedef unsigned short u16x4 __attribute__((ext_vector_type(4)));

#define B_SZ 32
#define N_SZ 512
#define FD_SZ 768
#define HD_SZ 384
#define G_SZ 3
#define M_SZ (B_SZ * N_SZ)   // 16384
#define ALPHA_LR 0.2f
#define NEGV -9.0e15f

__device__ __forceinline__ float bflo(uint_t u) { return __uint_as_float(u << 16); }
__device__ __forceinline__ float bfhi(uint_t u) { return __uint_as_float(u & 0xffff0000u); }
__device__ __forceinline__ float bf2f(ushort_t u) { return __uint_as_float(((uint_t)u) << 16); }
__device__ __forceinline__ ushort_t f2bf(float f) {
  uint_t x = __float_as_uint(f);
  return (ushort_t)((x + 0x7fffu + ((x >> 16) & 1u)) >> 16);
}
__device__ __forceinline__ u32x4 pack8(f32x4 lo, f32x4 hi) {
  union { ushort_t us[8]; u32x4 v; } pk;
  pk.us[0] = f2bf(lo.x); pk.us[1] = f2bf(lo.y); pk.us[2] = f2bf(lo.z); pk.us[3] = f2bf(lo.w);
  pk.us[4] = f2bf(hi.x); pk.us[5] = f2bf(hi.y); pk.us[6] = f2bf(hi.z); pk.us[7] = f2bf(hi.w);
  return pk.v;
}

// ---------------------------------------------------------------------------
// Transpose + downcast: dst[c*R + r] = bf16(src[r*C + c]), batched over z.
// ---------------------------------------------------------------------------
__global__ __launch_bounds__(256) void transpose_f2b(
    const float* __restrict__ src, ushort_t* __restrict__ dst, int R, int C) {
  size_t total = (size_t)R * C;
  size_t base = (size_t)blockIdx.z * total;
  size_t i = (size_t)blockIdx.x * 256 + threadIdx.x;
  if (i < total) {
    int r = (int)(i / C), c = (int)(i % C);
    dst[base + (size_t)c * R + r] = f2bf(src[base + i]);
  }
}

// ---------------------------------------------------------------------------
// Content gates: cg[n][g] = softmax_g( mean_b(x[b,n,:]) @ gate_w + gate_b )
// ---------------------------------------------------------------------------
__global__ __launch_bounds__(256) void gate_kernel(
    const float* __restrict__ x, const float* __restrict__ gate_w,
    const float* __restrict__ gate_b, float* __restrict__ cg) {
  int n = blockIdx.x;
  int tid = threadIdx.x;
  float a0 = 0.f, a1 = 0.f, a2 = 0.f;
  for (int f = tid; f < FD_SZ; f += 256) {
    float s = 0.f;
#pragma unroll
    for (int b = 0; b < B_SZ; b++) s += x[((size_t)b * N_SZ + n) * FD_SZ + f];
    float avg = s * (1.0f / B_SZ);
    a0 += avg * gate_w[f * 3 + 0];
    a1 += avg * gate_w[f * 3 + 1];
    a2 += avg * gate_w[f * 3 + 2];
  }
  for (int m = 1; m < 64; m <<= 1) {
    a0 += __shfl_xor(a0, m, 64);
    a1 += __shfl_xor(a1, m, 64);
    a2 += __shfl_xor(a2, m, 64);
  }
  __shared__ float red[3][4];
  int wave = tid >> 6, lane = tid & 63;
  if (lane == 0) { red[0][wave] = a0; red[1][wave] = a1; red[2][wave] = a2; }
  __syncthreads();
  if (tid == 0) {
    float l0 = red[0][0] + red[0][1] + red[0][2] + red[0][3] + gate_b[0];
    float l1 = red[1][0] + red[1][1] + red[1][2] + red[1][3] + gate_b[1];
    float l2 = red[2][0] + red[2][1] + red[2][2] + red[2][3] + gate_b[2];
    float mx = fmaxf(l0, fmaxf(l1, l2));
    float e0 = __expf(l0 - mx), e1 = __expf(l1 - mx), e2 = __expf(l2 - mx);
    float inv = 1.0f / (e0 + e1 + e2);
    cg[n * 3 + 0] = e0 * inv;
    cg[n * 3 + 1] = e1 * inv;
    cg[n * 3 + 2] = e2 * inv;
  }
}

// ---------------------------------------------------------------------------
// MFMA bf16 GEMM: C[M,Nc] = A[M,K] @ B[K,Nc] (+bias, +relu).
// A row-major [M,K]: f32 (downcast in staging) if AF32, else bf16.
// Bt row-major [Nc,K] bf16. 128x128 tile, BK=32, 4 waves 64x64 each.
// HTOUT: write C transposed as hT[z][n][m] bf16 (m-stride M_SZ), 4-packed.
// ---------------------------------------------------------------------------
template <bool AF32, bool RELU, bool OUTBF16, bool HASBIAS, bool HTOUT>
__global__ __launch_bounds__(256) void gemm_kernel(
    const void* __restrict__ Av, size_t strideA,
    const ushort_t* __restrict__ Bt, size_t strideB,
    const float* __restrict__ bias,
    void* __restrict__ Cv, size_t strideC,
    int M, int K, int Nc) {
  __shared__ __attribute__((aligned(16))) ushort_t As[128 * 32];
  __shared__ __attribute__((aligned(16))) ushort_t Bs[128 * 32];
  int tid = threadIdx.x, wave = tid >> 6, lane = tid & 63;
  int m0 = blockIdx.y * 128, n0 = blockIdx.x * 128;
  const float* Abf32 = (const float*)Av + (size_t)blockIdx.z * strideA;
  const ushort_t* Abb16 = (const ushort_t*)Av + (size_t)blockIdx.z * strideA;
  const ushort_t* Bb = Bt + (size_t)blockIdx.z * strideB;

  f32x4 acc[4][4];
  f32x4 z4 = {0.f, 0.f, 0.f, 0.f};
#pragma unroll
  for (int i = 0; i < 4; i++)
#pragma unroll
    for (int j = 0; j < 4; j++) acc[i][j] = z4;

  int wm = (wave & 1) * 64, wn = (wave >> 1) * 64;
  int srow = lane >> 2, schk = (lane & 3) * 8;

  for (int kt = 0; kt < K; kt += 32) {
    u32x4 av[2], bv[2];
#pragma unroll
    for (int i = 0; i < 2; i++) {
      int row = m0 + wave * 32 + i * 16 + srow;
      if (AF32) {
        const float* ap = Abf32 + (size_t)row * K + kt + schk;
        f32x4 lo = *(const f32x4*)ap;
        f32x4 hi = *(const f32x4*)(ap + 4);
        av[i] = pack8(lo, hi);
      } else {
        av[i] = *(const u32x4*)(Abb16 + (size_t)row * K + kt + schk);
      }
      bv[i] = *(const u32x4*)(Bb + (size_t)(n0 + wave * 32 + i * 16 + srow) * K + kt + schk);
    }
    __syncthreads();  // previous tile's frag reads done
#pragma unroll
    for (int i = 0; i < 2; i++) {
      int rowBase = wave * 32 + i * 16;
      *(u32x4*)(As + rowBase * 32 + lane * 8) = av[i];
      *(u32x4*)(Bs + rowBase * 32 + lane * 8) = bv[i];
    }
    __syncthreads();
    bf16x8 af[4], bfr[4];
#pragma unroll
    for (int t = 0; t < 4; t++) {
      af[t] = *(const bf16x8*)(As + (wm + t * 16 + (lane & 15)) * 32 + (lane >> 4) * 8);
      bfr[t] = *(const bf16x8*)(Bs + (wn + t * 16 + (lane & 15)) * 32 + (lane >> 4) * 8);
    }
#pragma unroll
    for (int mt = 0; mt < 4; mt++)
#pragma unroll
      for (int nt = 0; nt < 4; nt++)
        acc[mt][nt] = __builtin_amdgcn_mfma_f32_16x16x32_bf16(af[mt], bfr[nt], acc[mt][nt], 0, 0, 0);
  }

  if (HTOUT) {
    // hT[z][n][m]: per lane, 4 consecutive m (quad*4+r) at fixed n -> 8B store
#pragma unroll
    for (int mt = 0; mt < 4; mt++) {
#pragma unroll
      for (int nt = 0; nt < 4; nt++) {
        int gn = n0 + wn + nt * 16 + (lane & 15);
        int gm = m0 + wm + mt * 16 + (lane >> 4) * 4;
        u16x4 pk;
#pragma unroll
        for (int r2 = 0; r2 < 4; r2++) pk[r2] = f2bf(acc[mt][nt][r2]);
        *(u16x4*)((ushort_t*)Cv + (size_t)blockIdx.z * strideC + (size_t)gn * M_SZ + gm) = pk;
      }
    }
  } else {
#pragma unroll
    for (int mt = 0; mt < 4; mt++) {
#pragma unroll
      for (int nt = 0; nt < 4; nt++) {
        int gn = n0 + wn + nt * 16 + (lane & 15);
        float bvs = HASBIAS ? bias[gn] : 0.f;
#pragma unroll
        for (int r2 = 0; r2 < 4; r2++) {
          int gm = m0 + wm + mt * 16 + (lane >> 4) * 4 + r2;
          float v = acc[mt][nt][r2] + bvs;
          if (RELU) v = v > 0.f ? v : 0.f;
          size_t off = (size_t)blockIdx.z * strideC + (size_t)gm * Nc + gn;
          if (OUTBF16) ((ushort_t*)Cv)[off] = f2bf(v);
          else ((float*)Cv)[off] = v;
        }
      }
    }
  }
}

// ---------------------------------------------------------------------------
// e1[g,m] = sum_d hT[g][d][m]*a1[d];  e2 likewise with a2. Lane-coalesced in m.
// grid: (M/256, G)
// ---------------------------------------------------------------------------
__global__ __launch_bounds__(256) void e12_kernel(
    const ushort_t* __restrict__ hT, const float* __restrict__ a,
    float* __restrict__ e1, float* __restrict__ e2) {
  __shared__ float a1s[HD_SZ], a2s[HD_SZ];
  int g = blockIdx.y;
  int tid = threadIdx.x;
  for (int i = tid; i < HD_SZ; i += 256) {
    a1s[i] = a[g * 2 * HD_SZ + i];
    a2s[i] = a[g * 2 * HD_SZ + HD_SZ + i];
  }
  __syncthreads();
  int m = blockIdx.x * 256 + tid;
  const ushort_t* col = hT + (size_t)g * HD_SZ * M_SZ + m;
  float s1 = 0.f, s2 = 0.f;
  for (int d = 0; d < HD_SZ; d++) {
    float h = bf2f(col[(size_t)d * M_SZ]);
    s1 += h * a1s[d];
    s2 += h * a2s[d];
  }
  e1[(size_t)g * M_SZ + m] = s1;
  e2[(size_t)g * M_SZ + m] = s2;
}

// ---------------------------------------------------------------------------
// Attention (MFMA PV) + ELU + LN1 + g-weighted fuse.
// One block = (b, 16 query rows). Wave w owns d in [w*96, w*96+96).
// P normalized to bf16 in LDS (A-operand layout); V = hT read from global.
// ---------------------------------------------------------------------------
__global__ __launch_bounds__(256) void attn_kernel(
    const int* __restrict__ adj, const ushort_t* __restrict__ hT,
    const float* __restrict__ e1, const float* __restrict__ e2,
    const float* __restrict__ cg, const float* __restrict__ log_unc,
    const float* __restrict__ ln1g, const float* __restrict__ ln1b,
    ushort_t* __restrict__ fusedbf) {
  __shared__ __attribute__((aligned(16))) ushort_t Pb[16][520];  // +8 pad: 2-way free
  __shared__ float e2s[512];
  __shared__ float e1r[16];
  __shared__ float lng[HD_SZ], lnb[HD_SZ];
  __shared__ float cgr[16][3];
  __shared__ float s1s[16][4], s2s[16][4];

  int tid = threadIdx.x, wave = tid >> 6, lane = tid & 63;
  int quad = lane >> 4, l15 = lane & 15;
  int b = blockIdx.y, i0 = blockIdx.x * 16;

  float iv0 = 1.f / (__expf(log_unc[0]) + 1e-8f);
  float iv1 = 1.f / (__expf(log_unc[1]) + 1e-8f);
  float iv2 = 1.f / (__expf(log_unc[2]) + 1e-8f);
  float mxa = fmaxf(iv0, fmaxf(iv1, iv2));
  float w0 = __expf(iv0 - mxa), w1 = __expf(iv1 - mxa), w2 = __expf(iv2 - mxa);
  float wsum = 1.f / (w0 + w1 + w2);
  float attw[3] = {w0 * wsum, w1 * wsum, w2 * wsum};

  for (int idx = tid; idx < HD_SZ; idx += 256) {
    lng[idx] = ln1g[idx];
    lnb[idx] = ln1b[idx];
  }
  if (tid < 48) cgr[tid / 3][tid % 3] = cg[(i0 + tid / 3) * 3 + tid % 3];

  float facc[24];
#pragma unroll
  for (int t = 0; t < 24; t++) facc[t] = 0.f;

  for (int g = 0; g < G_SZ; g++) {
    __syncthreads();  // previous iteration's LDS readers done
    if (tid < 16) e1r[tid] = e1[((size_t)g * B_SZ + b) * N_SZ + i0 + tid];
    for (int idx = tid; idx < N_SZ; idx += 256)
      e2s[idx] = e2[((size_t)g * B_SZ + b) * N_SZ + idx];
    __syncthreads();

    // scores + softmax, in-register; wave owns rows wave*4 .. wave*4+3
#pragma unroll
    for (int rr = 0; rr < 4; rr++) {
      int rw = wave * 4 + rr;
      const int* arow = adj + ((size_t)g * N_SZ + i0 + rw) * N_SZ;
      float e1v = e1r[rw];
      float sv[8];
      float m = -3.0e38f;
#pragma unroll
      for (int jj = 0; jj < 8; jj++) {
        int j = lane + jj * 64;
        float s = e1v + e2s[j];
        s = s > 0.f ? s : ALPHA_LR * s;
        s = arow[j] > 0 ? s : NEGV;
        sv[jj] = s;
        m = fmaxf(m, s);
      }
      for (int msk = 1; msk < 64; msk <<= 1) m = fmaxf(m, __shfl_xor(m, msk, 64));
      float sum = 0.f;
#pragma unroll
      for (int jj = 0; jj < 8; jj++) {
        float e = __expf(sv[jj] - m);
        sv[jj] = e;
        sum += e;
      }
      for (int msk = 1; msk < 64; msk <<= 1) sum += __shfl_xor(sum, msk, 64);
      float inv = 1.0f / sum;
#pragma unroll
      for (int jj = 0; jj < 8; jj++) Pb[rw][lane + jj * 64] = f2bf(sv[jj] * inv);
    }
    __syncthreads();

    // PV via MFMA: O[16 x 96-per-wave] = P[16 x 512] @ hT^T
    f32x4 acc[6];
    f32x4 z4 = {0.f, 0.f, 0.f, 0.f};
#pragma unroll
    for (int t = 0; t < 6; t++) acc[t] = z4;
    const ushort_t* hTg = hT + (size_t)g * HD_SZ * M_SZ + (size_t)b * N_SZ;
    int dbase = wave * 96 + l15;
    for (int j0 = 0; j0 < N_SZ; j0 += 32) {
      bf16x8 af = *(const bf16x8*)(&Pb[l15][j0 + quad * 8]);
#pragma unroll
      for (int t = 0; t < 6; t++) {
        bf16x8 bf = *(const bf16x8*)(hTg + (size_t)(dbase + t * 16) * M_SZ + j0 + quad * 8);
        acc[t] = __builtin_amdgcn_mfma_f32_16x16x32_bf16(af, bf, acc[t], 0, 0, 0);
      }
    }

    // epilogue: ELU, LN over HD per query row (row = quad*4+r), weight, accum
    float o[24];
    float ps1[4] = {0.f, 0.f, 0.f, 0.f}, ps2[4] = {0.f, 0.f, 0.f, 0.f};
#pragma unroll
    for (int t = 0; t < 6; t++)
#pragma unroll
      for (int r = 0; r < 4; r++) {
        float v = acc[t][r];
        v = v > 0.f ? v : __expf(v) - 1.f;
        o[t * 4 + r] = v;
        ps1[r] += v;
        ps2[r] += v * v;
      }
#pragma unroll
    for (int msk = 1; msk < 16; msk <<= 1) {
#pragma unroll
      for (int r = 0; r < 4; r++) {
        ps1[r] += __shfl_xor(ps1[r], msk, 64);
        ps2[r] += __shfl_xor(ps2[r], msk, 64);
      }
    }
    if (l15 == 0) {
#pragma unroll
      for (int r = 0; r < 4; r++) {
        s1s[quad * 4 + r][wave] = ps1[r];
        s2s[quad * 4 + r][wave] = ps2[r];
      }
    }
    __syncthreads();
#pragma unroll
    for (int r = 0; r < 4; r++) {
      int row = quad * 4 + r;
      float S1 = s1s[row][0] + s1s[row][1] + s1s[row][2] + s1s[row][3];
      float S2 = s2s[row][0] + s2s[row][1] + s2s[row][2] + s2s[row][3];
      float mean = S1 * (1.f / HD_SZ);
      float var = S2 * (1.f / HD_SZ) - mean * mean;
      float rs = rsqrtf(var + 1e-5f);
      float wgt = 0.7f * attw[g] + 0.3f * cgr[row][g];
#pragma unroll
      for (int t = 0; t < 6; t++) {
        int d = wave * 96 + t * 16 + l15;
        facc[t * 4 + r] += wgt * ((o[t * 4 + r] - mean) * rs * lng[d] + lnb[d]);
      }
    }
  }
  // write fused bf16 [b][i0+row][d]
#pragma unroll
  for (int r = 0; r < 4; r++) {
    size_t rowo = ((size_t)b * N_SZ + i0 + quad * 4 + r) * HD_SZ;
#pragma unroll
    for (int t = 0; t < 6; t++)
      fusedbf[rowo + wave * 96 + t * 16 + l15] = f2bf(facc[t * 4 + r]);
  }
}

// ---------------------------------------------------------------------------
// LN2 + residual sigmoid gate. One block per (b,n) row. proj bf16, x/out f32.
// ---------------------------------------------------------------------------
__global__ __launch_bounds__(256) void final_kernel(
    const ushort_t* __restrict__ projbf, const float* __restrict__ x,
    const float* __restrict__ ln2g, const float* __restrict__ ln2b,
    float* __restrict__ out) {
  int row = blockIdx.x;
  int tid = threadIdx.x, wave = tid >> 6, lane = tid & 63;
  const ushort_t* pr = projbf + (size_t)row * FD_SZ;
  const float* xr = x + (size_t)row * FD_SZ;
  float v[3], xv[3];
  float s1 = 0.f, s2 = 0.f;
#pragma unroll
  for (int k = 0; k < 3; k++) {
    int c = tid + k * 256;
    v[k] = bf2f(pr[c]);
    xv[k] = xr[c];
    s1 += v[k];
    s2 += v[k] * v[k];
  }
  for (int m = 1; m < 64; m <<= 1) {
    s1 += __shfl_xor(s1, m, 64);
    s2 += __shfl_xor(s2, m, 64);
  }
  __shared__ float rs1[4], rs2[4], rdt[4];
  if (lane == 0) { rs1[wave] = s1; rs2[wave] = s2; }
  __syncthreads();
  s1 = rs1[0] + rs1[1] + rs1[2] + rs1[3];
  s2 = rs2[0] + rs2[1] + rs2[2] + rs2[3];
  float mean = s1 * (1.f / FD_SZ);
  float var = s2 * (1.f / FD_SZ) - mean * mean;
  float rstd = rsqrtf(var + 1e-5f);
  float dot = 0.f;
  float pn[3];
#pragma unroll
  for (int k = 0; k < 3; k++) {
    int c = tid + k * 256;
    pn[k] = (v[k] - mean) * rstd * ln2g[c] + ln2b[c];
    dot += pn[k] * xv[k];
  }
  for (int m = 1; m < 64; m <<= 1) dot += __shfl_xor(dot, m, 64);
  if (lane == 0) rdt[wave] = dot;
  __syncthreads();
  dot = rdt[0] + rdt[1] + rdt[2] + rdt[3];
  float gv = 1.f / (1.f + __expf(-dot * (1.0f / 27.712812921102035f)));  // /sqrt(768)
#pragma unroll
  for (int k = 0; k < 3; k++) {
    int c = tid + k * 256;
    out[(size_t)row * FD_SZ + c] = gv * xv[k] + (1.f - gv) * pn[k];
  }
}

// ---------------------------------------------------------------------------
extern "C" void kernel_launch(void* const* d_in, const int* in_sizes, int n_in,
                              void* d_out, int out_size, void* d_ws, size_t ws_size,
                              hipStream_t stream) {
  (void)in_sizes; (void)n_in; (void)out_size; (void)ws_size;
  const float* x = (const float*)d_in[0];
  const int* adj = (const int*)d_in[1];
  const float* W = (const float*)d_in[2];
  const float* a = (const float*)d_in[3];
  const float* log_unc = (const float*)d_in[4];
  const float* gate_w = (const float*)d_in[5];
  const float* gate_b = (const float*)d_in[6];
  const float* ln1g = (const float*)d_in[7];
  const float* ln1b = (const float*)d_in[8];
  const float* w1 = (const float*)d_in[9];
  const float* b1 = (const float*)d_in[10];
  const float* w2 = (const float*)d_in[11];
  const float* b2 = (const float*)d_in[12];
  const float* ln2g = (const float*)d_in[13];
  const float* ln2b = (const float*)d_in[14];

  // Workspace (peak 53,385,216 B ≈ 50.9 MiB, liveness-overlapped):
  //  [0          ) Wt      1,769,472   (bf16 [G][HD][FD])
  //  [1,769,472  ) w1t     294,912
  //  [2,064,384  ) w2t     589,824
  //  [2,654,208  ) cg      6,144
  //  [2,660,352  ) e1      196,608
  //  [2,856,960  ) e2      196,608
  //  [3,053,568  ) fusedbf 12,582,912  (attn -> t1 GEMM)
  //  [15,636,480 ) hT      37,748,736  ([G][HD][M] bf16; h GEMM -> attn); reused:
  //  [15,636,480 )   t1bf    12,582,912
  //  [28,219,392 )   projbf  25,165,824
  char* ws = (char*)d_ws;
  ushort_t* Wt      = (ushort_t*)(ws + 0);
  ushort_t* w1t     = (ushort_t*)(ws + 1769472);
  ushort_t* w2t     = (ushort_t*)(ws + 2064384);
  float*    cg      = (float*)(ws + 2654208);
  float*    e1      = (float*)(ws + 2660352);
  float*    e2      = (float*)(ws + 2856960);
  ushort_t* fusedbf = (ushort_t*)(ws + 3053568);
  ushort_t* hT      = (ushort_t*)(ws + 15636480);
  ushort_t* t1bf    = (ushort_t*)(ws + 15636480);   // over dead hT
  ushort_t* projbf  = (ushort_t*)(ws + 28219392);   // over dead hT

  transpose_f2b<<<dim3(1152, 1, 3), 256, 0, stream>>>(W, Wt, FD_SZ, HD_SZ);
  transpose_f2b<<<dim3(576, 1, 1), 256, 0, stream>>>(w1, w1t, HD_SZ, HD_SZ);
  transpose_f2b<<<dim3(1152, 1, 1), 256, 0, stream>>>(w2, w2t, HD_SZ, FD_SZ);

  gate_kernel<<<dim3(N_SZ), 256, 0, stream>>>(x, gate_w, gate_b, cg);

  // hT[g] = (x @ W[g])^T, written transposed from the C-fragments
  gemm_kernel<true, false, true, false, true><<<dim3(3, 128, 3), 256, 0, stream>>>(
      x, 0, Wt, (size_t)HD_SZ * FD_SZ, nullptr, hT, (size_t)HD_SZ * M_SZ,
      M_SZ, FD_SZ, HD_SZ);

  e12_kernel<<<dim3(M_SZ / 256, G_SZ), 256, 0, stream>>>(hT, a, e1, e2);

  attn_kernel<<<dim3(N_SZ / 16, B_SZ), 256, 0, stream>>>(
      adj, hT, e1, e2, cg, log_unc, ln1g, ln1b, fusedbf);

  // t1 = relu(fused @ w1 + b1)
  gemm_kernel<false, true, true, true, false><<<dim3(3, 128, 1), 256, 0, stream>>>(
      fusedbf, 0, w1t, 0, b1, t1bf, 0, M_SZ, HD_SZ, HD_SZ);
  // proj = t1 @ w2 + b2 (bf16 out)
  gemm_kernel<false, false, true, true, false><<<dim3(6, 128, 1), 256, 0, stream>>>(
      t1bf, 0, w2t, 0, b2, projbf, 0, M_SZ, HD_SZ, FD_SZ);

  final_kernel<<<dim3(M_SZ), 256, 0, stream>>>(projbf, x, ln2g, ln2b, (float*)d_out);
}

// Round 6
// 367.911 us; speedup vs baseline: 2.2291x; 1.1690x over previous
//
#include <hip/hip_runtime.h>

typedef unsigned short ushort_t;
typedef unsigned int uint_t;
typedef __bf16 bf16x8 __attribute__((ext_vector_type(8)));
typedef float f32x4 __attribute__((ext_vector_type(4)));
typedef unsigned int u32x4 __attribute__((ext_vector_type(4)));
typedef unsigned short u16x4 __attribute__((ext_vector_type(4)));

#define B_SZ 32
#define N_SZ 512
#define FD_SZ 768
#define HD_SZ 384
#define G_SZ 3
#define M_SZ (B_SZ * N_SZ)   // 16384
#define ALPHA_LR 0.2f
#define NEGV -9.0e15f
#define VTILE (HD_SZ * 32)   // elements per (g,b,jt) V-tile: 384 d x 32 j

__device__ __forceinline__ float bflo(uint_t u) { return __uint_as_float(u << 16); }
__device__ __forceinline__ float bfhi(uint_t u) { return __uint_as_float(u & 0xffff0000u); }
__device__ __forceinline__ float bf2f(ushort_t u) { return __uint_as_float(((uint_t)u) << 16); }
__device__ __forceinline__ ushort_t f2bf(float f) {
  uint_t x = __float_as_uint(f);
  return (ushort_t)((x + 0x7fffu + ((x >> 16) & 1u)) >> 16);
}
__device__ __forceinline__ u32x4 pack8(f32x4 lo, f32x4 hi) {
  union { ushort_t us[8]; u32x4 v; } pk;
  pk.us[0] = f2bf(lo.x); pk.us[1] = f2bf(lo.y); pk.us[2] = f2bf(lo.z); pk.us[3] = f2bf(lo.w);
  pk.us[4] = f2bf(hi.x); pk.us[5] = f2bf(hi.y); pk.us[6] = f2bf(hi.z); pk.us[7] = f2bf(hi.w);
  return pk.v;
}

// ---------------------------------------------------------------------------
// Transpose + downcast: dst[c*R + r] = bf16(src[r*C + c]), batched over z.
// ---------------------------------------------------------------------------
__global__ __launch_bounds__(256) void transpose_f2b(
    const float* __restrict__ src, ushort_t* __restrict__ dst, int R, int C) {
  size_t total = (size_t)R * C;
  size_t base = (size_t)blockIdx.z * total;
  size_t i = (size_t)blockIdx.x * 256 + threadIdx.x;
  if (i < total) {
    int r = (int)(i / C), c = (int)(i % C);
    dst[base + (size_t)c * R + r] = f2bf(src[base + i]);
  }
}

// ---------------------------------------------------------------------------
// Content gates: cg[n][g] = softmax_g( mean_b(x[b,n,:]) @ gate_w + gate_b )
// ---------------------------------------------------------------------------
__global__ __launch_bounds__(256) void gate_kernel(
    const float* __restrict__ x, const float* __restrict__ gate_w,
    const float* __restrict__ gate_b, float* __restrict__ cg) {
  int n = blockIdx.x;
  int tid = threadIdx.x;
  float a0 = 0.f, a1 = 0.f, a2 = 0.f;
  for (int f = tid; f < FD_SZ; f += 256) {
    float s = 0.f;
#pragma unroll
    for (int b = 0; b < B_SZ; b++) s += x[((size_t)b * N_SZ + n) * FD_SZ + f];
    float avg = s * (1.0f / B_SZ);
    a0 += avg * gate_w[f * 3 + 0];
    a1 += avg * gate_w[f * 3 + 1];
    a2 += avg * gate_w[f * 3 + 2];
  }
  for (int m = 1; m < 64; m <<= 1) {
    a0 += __shfl_xor(a0, m, 64);
    a1 += __shfl_xor(a1, m, 64);
    a2 += __shfl_xor(a2, m, 64);
  }
  __shared__ float red[3][4];
  int wave = tid >> 6, lane = tid & 63;
  if (lane == 0) { red[0][wave] = a0; red[1][wave] = a1; red[2][wave] = a2; }
  __syncthreads();
  if (tid == 0) {
    float l0 = red[0][0] + red[0][1] + red[0][2] + red[0][3] + gate_b[0];
    float l1 = red[1][0] + red[1][1] + red[1][2] + red[1][3] + gate_b[1];
    float l2 = red[2][0] + red[2][1] + red[2][2] + red[2][3] + gate_b[2];
    float mx = fmaxf(l0, fmaxf(l1, l2));
    float e0 = __expf(l0 - mx), e1 = __expf(l1 - mx), e2 = __expf(l2 - mx);
    float inv = 1.0f / (e0 + e1 + e2);
    cg[n * 3 + 0] = e0 * inv;
    cg[n * 3 + 1] = e1 * inv;
    cg[n * 3 + 2] = e2 * inv;
  }
}

// ---------------------------------------------------------------------------
// MFMA bf16 GEMM: C[M,Nc] = A[M,K] @ B[K,Nc] (+bias, +relu).
// A row-major [M,K]: f32 (downcast in staging) if AF32, else bf16.
// Bt row-major [Nc,K] bf16. 128x128 tile, BK=32, 4 waves 64x64 each.
// VFOUT: write C as V-tiles vf[(z*32+b)*16+jt][d=0..384)[j2=0..32) bf16,
//        where m = b*512 + jt*32 + j2, n = d. (B-frag-native layout.)
// ---------------------------------------------------------------------------
template <bool AF32, bool RELU, bool OUTBF16, bool HASBIAS, bool VFOUT>
__global__ __launch_bounds__(256) void gemm_kernel(
    const void* __restrict__ Av, size_t strideA,
    const ushort_t* __restrict__ Bt, size_t strideB,
    const float* __restrict__ bias,
    void* __restrict__ Cv, size_t strideC,
    int M, int K, int Nc) {
  __shared__ __attribute__((aligned(16))) ushort_t As[128 * 32];
  __shared__ __attribute__((aligned(16))) ushort_t Bs[128 * 32];
  int tid = threadIdx.x, wave = tid >> 6, lane = tid & 63;
  int m0 = blockIdx.y * 128, n0 = blockIdx.x * 128;
  const float* Abf32 = (const float*)Av + (size_t)blockIdx.z * strideA;
  const ushort_t* Abb16 = (const ushort_t*)Av + (size_t)blockIdx.z * strideA;
  const ushort_t* Bb = Bt + (size_t)blockIdx.z * strideB;

  f32x4 acc[4][4];
  f32x4 z4 = {0.f, 0.f, 0.f, 0.f};
#pragma unroll
  for (int i = 0; i < 4; i++)
#pragma unroll
    for (int j = 0; j < 4; j++) acc[i][j] = z4;

  int wm = (wave & 1) * 64, wn = (wave >> 1) * 64;
  int srow = lane >> 2, schk = (lane & 3) * 8;

  for (int kt = 0; kt < K; kt += 32) {
    u32x4 av[2], bv[2];
#pragma unroll
    for (int i = 0; i < 2; i++) {
      int row = m0 + wave * 32 + i * 16 + srow;
      if (AF32) {
        const float* ap = Abf32 + (size_t)row * K + kt + schk;
        f32x4 lo = *(const f32x4*)ap;
        f32x4 hi = *(const f32x4*)(ap + 4);
        av[i] = pack8(lo, hi);
      } else {
        av[i] = *(const u32x4*)(Abb16 + (size_t)row * K + kt + schk);
      }
      bv[i] = *(const u32x4*)(Bb + (size_t)(n0 + wave * 32 + i * 16 + srow) * K + kt + schk);
    }
    __syncthreads();  // previous tile's frag reads done
#pragma unroll
    for (int i = 0; i < 2; i++) {
      int rowBase = wave * 32 + i * 16;
      *(u32x4*)(As + rowBase * 32 + lane * 8) = av[i];
      *(u32x4*)(Bs + rowBase * 32 + lane * 8) = bv[i];
    }
    __syncthreads();
    bf16x8 af[4], bfr[4];
#pragma unroll
    for (int t = 0; t < 4; t++) {
      af[t] = *(const bf16x8*)(As + (wm + t * 16 + (lane & 15)) * 32 + (lane >> 4) * 8);
      bfr[t] = *(const bf16x8*)(Bs + (wn + t * 16 + (lane & 15)) * 32 + (lane >> 4) * 8);
    }
#pragma unroll
    for (int mt = 0; mt < 4; mt++)
#pragma unroll
      for (int nt = 0; nt < 4; nt++)
        acc[mt][nt] = __builtin_amdgcn_mfma_f32_16x16x32_bf16(af[mt], bfr[nt], acc[mt][nt], 0, 0, 0);
  }

  if (VFOUT) {
    // per lane: 4 consecutive m at fixed n=d -> one 8B store inside a V-tile
#pragma unroll
    for (int mt = 0; mt < 4; mt++) {
#pragma unroll
      for (int nt = 0; nt < 4; nt++) {
        int d = n0 + wn + nt * 16 + (lane & 15);
        int gm = m0 + wm + mt * 16 + (lane >> 4) * 4;
        int b = gm >> 9, jt = (gm >> 5) & 15, j2 = gm & 31;
        u16x4 pk;
#pragma unroll
        for (int r2 = 0; r2 < 4; r2++) pk[r2] = f2bf(acc[mt][nt][r2]);
        size_t off = ((size_t)((blockIdx.z * B_SZ + b) * 16 + jt)) * VTILE + (size_t)d * 32 + j2;
        *(u16x4*)((ushort_t*)Cv + off) = pk;
      }
    }
  } else {
#pragma unroll
    for (int mt = 0; mt < 4; mt++) {
#pragma unroll
      for (int nt = 0; nt < 4; nt++) {
        int gn = n0 + wn + nt * 16 + (lane & 15);
        float bvs = HASBIAS ? bias[gn] : 0.f;
#pragma unroll
        for (int r2 = 0; r2 < 4; r2++) {
          int gm = m0 + wm + mt * 16 + (lane >> 4) * 4 + r2;
          float v = acc[mt][nt][r2] + bvs;
          if (RELU) v = v > 0.f ? v : 0.f;
          size_t off = (size_t)blockIdx.z * strideC + (size_t)gm * Nc + gn;
          if (OUTBF16) ((ushort_t*)Cv)[off] = f2bf(v);
          else ((float*)Cv)[off] = v;
        }
      }
    }
  }
}

// ---------------------------------------------------------------------------
// e1[g,m] = sum_d V[g][m][d]*a1[d];  e2 likewise. V in tiled vf layout.
// grid: (M/256, G); thread -> m, reads stride-32-elem columns (64B granular).
// ---------------------------------------------------------------------------
__global__ __launch_bounds__(256) void e12_kernel(
    const ushort_t* __restrict__ vf, const float* __restrict__ a,
    float* __restrict__ e1, float* __restrict__ e2) {
  __shared__ float a1s[HD_SZ], a2s[HD_SZ];
  int g = blockIdx.y;
  int tid = threadIdx.x;
  for (int i = tid; i < HD_SZ; i += 256) {
    a1s[i] = a[g * 2 * HD_SZ + i];
    a2s[i] = a[g * 2 * HD_SZ + HD_SZ + i];
  }
  __syncthreads();
  int m = blockIdx.x * 256 + tid;
  int b = m >> 9, jt = (m >> 5) & 15, j2 = m & 31;
  const ushort_t* col = vf + ((size_t)((g * B_SZ + b) * 16 + jt)) * VTILE + j2;
  float s1 = 0.f, s2 = 0.f;
  for (int d = 0; d < HD_SZ; d++) {
    float h = bf2f(col[d * 32]);
    s1 += h * a1s[d];
    s2 += h * a2s[d];
  }
  e1[(size_t)g * M_SZ + m] = s1;
  e2[(size_t)g * M_SZ + m] = s2;
}

// ---------------------------------------------------------------------------
// Attention (MFMA PV) + ELU + LN1 + g-weighted fuse.
// One block = (b, 16 query rows). Wave w owns d in [w*96, w*96+96).
// P normalized to bf16 in LDS (A-operand layout); V tiles read coalesced
// from vf (per (t): wave reads one contiguous 1KB chunk).
// ---------------------------------------------------------------------------
__global__ __launch_bounds__(256) void attn_kernel(
    const int* __restrict__ adj, const ushort_t* __restrict__ vf,
    const float* __restrict__ e1, const float* __restrict__ e2,
    const float* __restrict__ cg, const float* __restrict__ log_unc,
    const float* __restrict__ ln1g, const float* __restrict__ ln1b,
    ushort_t* __restrict__ fusedbf) {
  __shared__ __attribute__((aligned(16))) ushort_t Pb[16][520];  // +8 pad
  __shared__ float e2s[512];
  __shared__ float e1r[16];
  __shared__ float lng[HD_SZ], lnb[HD_SZ];
  __shared__ float cgr[16][3];
  __shared__ float s1s[16][4], s2s[16][4];

  int tid = threadIdx.x, wave = tid >> 6, lane = tid & 63;
  int quad = lane >> 4, l15 = lane & 15;
  int b = blockIdx.y, i0 = blockIdx.x * 16;

  float iv0 = 1.f / (__expf(log_unc[0]) + 1e-8f);
  float iv1 = 1.f / (__expf(log_unc[1]) + 1e-8f);
  float iv2 = 1.f / (__expf(log_unc[2]) + 1e-8f);
  float mxa = fmaxf(iv0, fmaxf(iv1, iv2));
  float w0 = __expf(iv0 - mxa), w1 = __expf(iv1 - mxa), w2 = __expf(iv2 - mxa);
  float wsum = 1.f / (w0 + w1 + w2);
  float attw[3] = {w0 * wsum, w1 * wsum, w2 * wsum};

  for (int idx = tid; idx < HD_SZ; idx += 256) {
    lng[idx] = ln1g[idx];
    lnb[idx] = ln1b[idx];
  }
  if (tid < 48) cgr[tid / 3][tid % 3] = cg[(i0 + tid / 3) * 3 + tid % 3];

  float facc[24];
#pragma unroll
  for (int t = 0; t < 24; t++) facc[t] = 0.f;

  for (int g = 0; g < G_SZ; g++) {
    __syncthreads();  // previous iteration's LDS readers done
    if (tid < 16) e1r[tid] = e1[((size_t)g * B_SZ + b) * N_SZ + i0 + tid];
    for (int idx = tid; idx < N_SZ; idx += 256)
      e2s[idx] = e2[((size_t)g * B_SZ + b) * N_SZ + idx];
    __syncthreads();

    // scores + softmax, in-register; wave owns rows wave*4 .. wave*4+3
#pragma unroll
    for (int rr = 0; rr < 4; rr++) {
      int rw = wave * 4 + rr;
      const int* arow = adj + ((size_t)g * N_SZ + i0 + rw) * N_SZ;
      float e1v = e1r[rw];
      float sv[8];
      float m = -3.0e38f;
#pragma unroll
      for (int jj = 0; jj < 8; jj++) {
        int j = lane + jj * 64;
        float s = e1v + e2s[j];
        s = s > 0.f ? s : ALPHA_LR * s;
        s = arow[j] > 0 ? s : NEGV;
        sv[jj] = s;
        m = fmaxf(m, s);
      }
      for (int msk = 1; msk < 64; msk <<= 1) m = fmaxf(m, __shfl_xor(m, msk, 64));
      float sum = 0.f;
#pragma unroll
      for (int jj = 0; jj < 8; jj++) {
        float e = __expf(sv[jj] - m);
        sv[jj] = e;
        sum += e;
      }
      for (int msk = 1; msk < 64; msk <<= 1) sum += __shfl_xor(sum, msk, 64);
      float inv = 1.0f / sum;
#pragma unroll
      for (int jj = 0; jj < 8; jj++) Pb[rw][lane + jj * 64] = f2bf(sv[jj] * inv);
    }
    __syncthreads();

    // PV via MFMA: O[16 x 96-per-wave] = P[16 x 512] @ V
    f32x4 acc[6];
    f32x4 z4 = {0.f, 0.f, 0.f, 0.f};
#pragma unroll
    for (int t = 0; t < 6; t++) acc[t] = z4;
    const ushort_t* vbase = vf + ((size_t)(g * B_SZ + b) * 16) * VTILE;
    for (int j0 = 0; j0 < N_SZ; j0 += 32) {
      bf16x8 af = *(const bf16x8*)(&Pb[l15][j0 + quad * 8]);
      const ushort_t* vtile = vbase + (size_t)(j0 >> 5) * VTILE;
#pragma unroll
      for (int t = 0; t < 6; t++) {
        bf16x8 bf = *(const bf16x8*)(vtile + (wave * 96 + t * 16 + l15) * 32 + quad * 8);
        acc[t] = __builtin_amdgcn_mfma_f32_16x16x32_bf16(af, bf, acc[t], 0, 0, 0);
      }
    }

    // epilogue: ELU, LN over HD per query row (row = quad*4+r), weight, accum
    float o[24];
    float ps1[4] = {0.f, 0.f, 0.f, 0.f}, ps2[4] = {0.f, 0.f, 0.f, 0.f};
#pragma unroll
    for (int t = 0; t < 6; t++)
#pragma unroll
      for (int r = 0; r < 4; r++) {
        float v = acc[t][r];
        v = v > 0.f ? v : __expf(v) - 1.f;
        o[t * 4 + r] = v;
        ps1[r] += v;
        ps2[r] += v * v;
      }
#pragma unroll
    for (int msk = 1; msk < 16; msk <<= 1) {
#pragma unroll
      for (int r = 0; r < 4; r++) {
        ps1[r] += __shfl_xor(ps1[r], msk, 64);
        ps2[r] += __shfl_xor(ps2[r], msk, 64);
      }
    }
    if (l15 == 0) {
#pragma unroll
      for (int r = 0; r < 4; r++) {
        s1s[quad * 4 + r][wave] = ps1[r];
        s2s[quad * 4 + r][wave] = ps2[r];
      }
    }
    __syncthreads();
#pragma unroll
    for (int r = 0; r < 4; r++) {
      int row = quad * 4 + r;
      float S1 = s1s[row][0] + s1s[row][1] + s1s[row][2] + s1s[row][3];
      float S2 = s2s[row][0] + s2s[row][1] + s2s[row][2] + s2s[row][3];
      float mean = S1 * (1.f / HD_SZ);
      float var = S2 * (1.f / HD_SZ) - mean * mean;
      float rs = rsqrtf(var + 1e-5f);
      float wgt = 0.7f * attw[g] + 0.3f * cgr[row][g];
#pragma unroll
      for (int t = 0; t < 6; t++) {
        int d = wave * 96 + t * 16 + l15;
        facc[t * 4 + r] += wgt * ((o[t * 4 + r] - mean) * rs * lng[d] + lnb[d]);
      }
    }
  }
  // write fused bf16 [b][i0+row][d]
#pragma unroll
  for (int r = 0; r < 4; r++) {
    size_t rowo = ((size_t)b * N_SZ + i0 + quad * 4 + r) * HD_SZ;
#pragma unroll
    for (int t = 0; t < 6; t++)
      fusedbf[rowo + wave * 96 + t * 16 + l15] = f2bf(facc[t * 4 + r]);
  }
}

// ---------------------------------------------------------------------------
// LN2 + residual sigmoid gate. One block per (b,n) row. proj bf16, x/out f32.
// ---------------------------------------------------------------------------
__global__ __launch_bounds__(256) void final_kernel(
    const ushort_t* __restrict__ projbf, const float* __restrict__ x,
    const float* __restrict__ ln2g, const float* __restrict__ ln2b,
    float* __restrict__ out) {
  int row = blockIdx.x;
  int tid = threadIdx.x, wave = tid >> 6, lane = tid & 63;
  const ushort_t* pr = projbf + (size_t)row * FD_SZ;
  const float* xr = x + (size_t)row * FD_SZ;
  float v[3], xv[3];
  float s1 = 0.f, s2 = 0.f;
#pragma unroll
  for (int k = 0; k < 3; k++) {
    int c = tid + k * 256;
    v[k] = bf2f(pr[c]);
    xv[k] = xr[c];
    s1 += v[k];
    s2 += v[k] * v[k];
  }
  for (int m = 1; m < 64; m <<= 1) {
    s1 += __shfl_xor(s1, m, 64);
    s2 += __shfl_xor(s2, m, 64);
  }
  __shared__ float rs1[4], rs2[4], rdt[4];
  if (lane == 0) { rs1[wave] = s1; rs2[wave] = s2; }
  __syncthreads();
  s1 = rs1[0] + rs1[1] + rs1[2] + rs1[3];
  s2 = rs2[0] + rs2[1] + rs2[2] + rs2[3];
  float mean = s1 * (1.f / FD_SZ);
  float var = s2 * (1.f / FD_SZ) - mean * mean;
  float rstd = rsqrtf(var + 1e-5f);
  float dot = 0.f;
  float pn[3];
#pragma unroll
  for (int k = 0; k < 3; k++) {
    int c = tid + k * 256;
    pn[k] = (v[k] - mean) * rstd * ln2g[c] + ln2b[c];
    dot += pn[k] * xv[k];
  }
  for (int m = 1; m < 64; m <<= 1) dot += __shfl_xor(dot, m, 64);
  if (lane == 0) rdt[wave] = dot;
  __syncthreads();
  dot = rdt[0] + rdt[1] + rdt[2] + rdt[3];
  float gv = 1.f / (1.f + __expf(-dot * (1.0f / 27.712812921102035f)));  // /sqrt(768)
#pragma unroll
  for (int k = 0; k < 3; k++) {
    int c = tid + k * 256;
    out[(size_t)row * FD_SZ + c] = gv * xv[k] + (1.f - gv) * pn[k];
  }
}

// ---------------------------------------------------------------------------
extern "C" void kernel_launch(void* const* d_in, const int* in_sizes, int n_in,
                              void* d_out, int out_size, void* d_ws, size_t ws_size,
                              hipStream_t stream) {
  (void)in_sizes; (void)n_in; (void)out_size; (void)ws_size;
  const float* x = (const float*)d_in[0];
  const int* adj = (const int*)d_in[1];
  const float* W = (const float*)d_in[2];
  const float* a = (const float*)d_in[3];
  const float* log_unc = (const float*)d_in[4];
  const float* gate_w = (const float*)d_in[5];
  const float* gate_b = (const float*)d_in[6];
  const float* ln1g = (const float*)d_in[7];
  const float* ln1b = (const float*)d_in[8];
  const float* w1 = (const float*)d_in[9];
  const float* b1 = (const float*)d_in[10];
  const float* w2 = (const float*)d_in[11];
  const float* b2 = (const float*)d_in[12];
  const float* ln2g = (const float*)d_in[13];
  const float* ln2b = (const float*)d_in[14];

  // Workspace (peak 53,385,216 B ≈ 50.9 MiB, liveness-overlapped):
  //  [0          ) Wt      1,769,472   (bf16 [G][HD][FD])
  //  [1,769,472  ) w1t     294,912
  //  [2,064,384  ) w2t     589,824
  //  [2,654,208  ) cg      6,144
  //  [2,660,352  ) e1      196,608
  //  [2,856,960  ) e2      196,608
  //  [3,053,568  ) fusedbf 12,582,912  (attn -> t1 GEMM)
  //  [15,636,480 ) vf      37,748,736  (tiled V; h GEMM -> attn); reused:
  //  [15,636,480 )   t1bf    12,582,912
  //  [28,219,392 )   projbf  25,165,824
  char* ws = (char*)d_ws;
  ushort_t* Wt      = (ushort_t*)(ws + 0);
  ushort_t* w1t     = (ushort_t*)(ws + 1769472);
  ushort_t* w2t     = (ushort_t*)(ws + 2064384);
  float*    cg      = (float*)(ws + 2654208);
  float*    e1      = (float*)(ws + 2660352);
  float*    e2      = (float*)(ws + 2856960);
  ushort_t* fusedbf = (ushort_t*)(ws + 3053568);
  ushort_t* vf      = (ushort_t*)(ws + 15636480);
  ushort_t* t1bf    = (ushort_t*)(ws + 15636480);   // over dead vf
  ushort_t* projbf  = (ushort_t*)(ws + 28219392);   // over dead vf

  transpose_f2b<<<dim3(1152, 1, 3), 256, 0, stream>>>(W, Wt, FD_SZ, HD_SZ);
  transpose_f2b<<<dim3(576, 1, 1), 256, 0, stream>>>(w1, w1t, HD_SZ, HD_SZ);
  transpose_f2b<<<dim3(1152, 1, 1), 256, 0, stream>>>(w2, w2t, HD_SZ, FD_SZ);

  gate_kernel<<<dim3(N_SZ), 256, 0, stream>>>(x, gate_w, gate_b, cg);

  // vf[g] = (x @ W[g]) in V-tile layout, written from the C-fragments
  gemm_kernel<true, false, true, false, true><<<dim3(3, 128, 3), 256, 0, stream>>>(
      x, 0, Wt, (size_t)HD_SZ * FD_SZ, nullptr, vf, 0,
      M_SZ, FD_SZ, HD_SZ);

  e12_kernel<<<dim3(M_SZ / 256, G_SZ), 256, 0, stream>>>(vf, a, e1, e2);

  attn_kernel<<<dim3(N_SZ / 16, B_SZ), 256, 0, stream>>>(
      adj, vf, e1, e2, cg, log_unc, ln1g, ln1b, fusedbf);

  // t1 = relu(fused @ w1 + b1)
  gemm_kernel<false, true, true, true, false><<<dim3(3, 128, 1), 256, 0, stream>>>(
      fusedbf, 0, w1t, 0, b1, t1bf, 0, M_SZ, HD_SZ, HD_SZ);
  // proj = t1 @ w2 + b2 (bf16 out)
  gemm_kernel<false, false, true, true, false><<<dim3(6, 128, 1), 256, 0, stream>>>(
      t1bf, 0, w2t, 0, b2, projbf, 0, M_SZ, HD_SZ, FD_SZ);

  final_kernel<<<dim3(M_SZ), 256, 0, stream>>>(projbf, x, ln2g, ln2b, (float*)d_out);
}